// Round 1
// 1505.690 us; speedup vs baseline: 1.5969x; 1.5969x over previous
//
#include <hip/hip_runtime.h>

// Attention fwd, B=4 H=16 L=2048 D=64, fp32 in/out, outputs Out then Attn.
//
// Round 2: move QK^T and PV onto the matrix cores via split-bf16 (3xMFMA).
//  - x = hi + lo (bf16 trunc); x*y ~= xh*yh + xh*yl + xl*yh, err <= 2^-16|xy|.
//  - mfma_f32_16x16x32_bf16; C/D layout (verified): col=lane&15, row=(lane>>4)*4+reg.
//    A/B loaded with identical contiguous-8 k-convention -> any k-permutation
//    mismatch vs HW cancels in the dot product.
//  - sweep 1: hi-only QK (rowsums only; rsum rel err ~2e-4 -> attn err ~1e-5),
//    in-wave shfl_xor row-sum reduction (no LDS, no extra barriers).
//  - sweep 2: 3-term QK -> exp*inv -> attn store; P packed (hi|lo u32) into
//    wave-private LDS (RAW is wave-local, compiler emits lgkmcnt, no barrier);
//    3-term PV from LDS-staged V^T.
//  - All LDS tiles [64][64] bf16 row-major with XOR swizzle col^=(row&7)<<3:
//    every b128 fragment read is bank-conflict-free.
//  - LDS 48 KB -> 3 blocks/CU (12 waves).

#define LL 2048
#define DD 64
#define HH 16
#define TQ 64
#define TK 64
#define NTH 256
#define NKT (LL / TK)

typedef __attribute__((ext_vector_type(8))) short bf16x8;
typedef __attribute__((ext_vector_type(4))) float f32x4;

__device__ __forceinline__ unsigned short bf_hi(float x) {
    return (unsigned short)(__float_as_uint(x) >> 16);   // truncating fp32->bf16
}
__device__ __forceinline__ float bf_f(unsigned short h) {
    return __uint_as_float(((unsigned int)h) << 16);
}
// [64][64] element arrays, row stride 64: XOR-swizzle 8-elem chunks per 8-row stripe
__device__ __forceinline__ int swz(int row, int col) {
    return (row << 6) + (col ^ ((row & 7) << 3));
}

__global__ __launch_bounds__(NTH, 3)
void attn_mfma(const float* __restrict__ Q, const float* __restrict__ K,
               const float* __restrict__ V, const float* __restrict__ M,
               float* __restrict__ Out, float* __restrict__ Attn)
{
    __shared__ __align__(16) unsigned short s_kh[TK * DD];  // K tile hi  [k][d] (also Q staging)
    __shared__ __align__(16) unsigned short s_kl[TK * DD];  // K tile lo
    __shared__ __align__(16) unsigned short s_vh[DD * TK];  // V^T tile hi [d][k]
    __shared__ __align__(16) unsigned short s_vl[DD * TK];  // V^T tile lo
    __shared__ __align__(16) unsigned int   s_p [TQ * TK];  // P packed (hi | lo<<16) [q][k]

    const int tid  = threadIdx.x;
    const int wid  = tid >> 6;        // wave 0..3: owns q-rows wid*16..+15
    const int lane = tid & 63;
    const int lg   = lane >> 4;       // 0..3
    const int ln   = lane & 15;       // 0..15

    const int bh  = blockIdx.y;
    const int b   = bh >> 4;          // HH = 16
    const int q0b = blockIdx.x * TQ;
    const size_t rowBH = (size_t)bh * LL;

    // staging map for row-major [64][64]: 4 threads/row, 4 float4 chunks each
    const int sr = tid >> 2;
    const int sc = (tid & 3) << 4;
    // staging map for V^T: thread -> d = tid&63, k-chunks (tid>>6)*4 + i*16
    const int vd  = tid & 63;
    const int vk0 = (tid >> 6) << 2;

    const float* Mrow = M + b * LL;
    const f32x4 fzero = {0.f, 0.f, 0.f, 0.f};

    // ---- stage Q tile (hi/lo) via s_kh/s_kl, pull fragments into registers ----
    {
        const float* qp = Q + (rowBH + q0b + sr) * DD;
        #pragma unroll
        for (int i = 0; i < 4; ++i) {
            float4 x = *(const float4*)(qp + sc + (i << 2));
            ushort4 h, l;
            h.x = bf_hi(x.x); l.x = bf_hi(x.x - bf_f(h.x));
            h.y = bf_hi(x.y); l.y = bf_hi(x.y - bf_f(h.y));
            h.z = bf_hi(x.z); l.z = bf_hi(x.z - bf_f(h.z));
            h.w = bf_hi(x.w); l.w = bf_hi(x.w - bf_f(h.w));
            int a = swz(sr, sc + (i << 2));
            *(ushort4*)&s_kh[a] = h;
            *(ushort4*)&s_kl[a] = l;
        }
    }
    __syncthreads();

    bf16x8 qh[2], ql[2];   // A-frag: row = ln (within wave's 16 rows), k = s*32+lg*8+e
    {
        const int qrow = (wid << 4) + ln;
        #pragma unroll
        for (int s = 0; s < 2; ++s) {
            int a = swz(qrow, (s << 5) + (lg << 3));
            qh[s] = *(const bf16x8*)&s_kh[a];
            ql[s] = *(const bf16x8*)&s_kl[a];
        }
    }
    __syncthreads();

    // ================= sweep 1: row sums of exp (hi-only QK) =================
    float esum[4] = {0.f, 0.f, 0.f, 0.f};

    for (int kt = 0; kt < NKT; ++kt) {
        {
            const float* kp = K + (rowBH + kt * TK + sr) * DD;
            #pragma unroll
            for (int i = 0; i < 4; ++i) {
                float4 x = *(const float4*)(kp + sc + (i << 2));
                ushort4 h;
                h.x = bf_hi(x.x); h.y = bf_hi(x.y);
                h.z = bf_hi(x.z); h.w = bf_hi(x.w);
                *(ushort4*)&s_kh[swz(sr, sc + (i << 2))] = h;
            }
        }
        __syncthreads();

        f32x4 acc[4];
        #pragma unroll
        for (int ct = 0; ct < 4; ++ct) acc[ct] = fzero;

        #pragma unroll
        for (int s = 0; s < 2; ++s) {
            #pragma unroll
            for (int ct = 0; ct < 4; ++ct) {
                bf16x8 kh = *(const bf16x8*)&s_kh[swz((ct << 4) + ln, (s << 5) + (lg << 3))];
                acc[ct] = __builtin_amdgcn_mfma_f32_16x16x32_bf16(qh[s], kh, acc[ct], 0, 0, 0);
            }
        }

        #pragma unroll
        for (int ct = 0; ct < 4; ++ct) {
            float mneg = Mrow[kt * TK + (ct << 4) + ln] * -1.0e9f;
            #pragma unroll
            for (int r = 0; r < 4; ++r)
                esum[r] += __expf(fmaf(acc[ct][r], 0.125f, mneg));
        }
        __syncthreads();
    }

    // reduce across the 16 lanes sharing lg (cols) -> full row sums, all in-wave
    #pragma unroll
    for (int m = 1; m <= 8; m <<= 1) {
        #pragma unroll
        for (int r = 0; r < 4; ++r)
            esum[r] += __shfl_xor(esum[r], m, 64);
    }
    float inv[4];
    #pragma unroll
    for (int r = 0; r < 4; ++r) inv[r] = 1.0f / esum[r];

    // ================= sweep 2: attn store + PV (full split) =================
    f32x4 oacc[4];
    #pragma unroll
    for (int dt = 0; dt < 4; ++dt) oacc[dt] = fzero;

    for (int kt = 0; kt < NKT; ++kt) {
        // stage K (hi+lo) and V^T (hi+lo)
        {
            const float* kp = K + (rowBH + kt * TK + sr) * DD;
            #pragma unroll
            for (int i = 0; i < 4; ++i) {
                float4 x = *(const float4*)(kp + sc + (i << 2));
                ushort4 h, l;
                h.x = bf_hi(x.x); l.x = bf_hi(x.x - bf_f(h.x));
                h.y = bf_hi(x.y); l.y = bf_hi(x.y - bf_f(h.y));
                h.z = bf_hi(x.z); l.z = bf_hi(x.z - bf_f(h.z));
                h.w = bf_hi(x.w); l.w = bf_hi(x.w - bf_f(h.w));
                int a = swz(sr, sc + (i << 2));
                *(ushort4*)&s_kh[a] = h;
                *(ushort4*)&s_kl[a] = l;
            }
            const float* vbase = V + (rowBH + kt * TK) * DD + vd;
            #pragma unroll
            for (int i = 0; i < 4; ++i) {
                int kb = vk0 + (i << 4);
                float x0 = vbase[(kb + 0) * DD];
                float x1 = vbase[(kb + 1) * DD];
                float x2 = vbase[(kb + 2) * DD];
                float x3 = vbase[(kb + 3) * DD];
                ushort4 h, l;
                h.x = bf_hi(x0); l.x = bf_hi(x0 - bf_f(h.x));
                h.y = bf_hi(x1); l.y = bf_hi(x1 - bf_f(h.y));
                h.z = bf_hi(x2); l.z = bf_hi(x2 - bf_f(h.z));
                h.w = bf_hi(x3); l.w = bf_hi(x3 - bf_f(h.w));
                int a = swz(vd, kb);
                *(ushort4*)&s_vh[a] = h;
                *(ushort4*)&s_vl[a] = l;
            }
        }
        __syncthreads();

        // QK^T, 3-term split
        f32x4 acc[4];
        #pragma unroll
        for (int ct = 0; ct < 4; ++ct) acc[ct] = fzero;

        #pragma unroll
        for (int s = 0; s < 2; ++s) {
            #pragma unroll
            for (int ct = 0; ct < 4; ++ct) {
                int a = swz((ct << 4) + ln, (s << 5) + (lg << 3));
                bf16x8 kh = *(const bf16x8*)&s_kh[a];
                bf16x8 kl = *(const bf16x8*)&s_kl[a];
                acc[ct] = __builtin_amdgcn_mfma_f32_16x16x32_bf16(qh[s], kh, acc[ct], 0, 0, 0);
                acc[ct] = __builtin_amdgcn_mfma_f32_16x16x32_bf16(qh[s], kl, acc[ct], 0, 0, 0);
                acc[ct] = __builtin_amdgcn_mfma_f32_16x16x32_bf16(ql[s], kh, acc[ct], 0, 0, 0);
            }
        }

        // normalize, store attn (fp32), pack P (hi|lo) into wave-private LDS
        float* ap = Attn + (rowBH + q0b + (wid << 4) + (lg << 2)) * (size_t)LL
                  + (size_t)kt * TK + ln;
        #pragma unroll
        for (int ct = 0; ct < 4; ++ct) {
            float mneg = Mrow[kt * TK + (ct << 4) + ln] * -1.0e9f;
            #pragma unroll
            for (int r = 0; r < 4; ++r) {
                float p = __expf(fmaf(acc[ct][r], 0.125f, mneg)) * inv[r];
                ap[(size_t)r * LL + (ct << 4)] = p;
                unsigned short php = bf_hi(p);
                unsigned short plp = bf_hi(p - bf_f(php));
                s_p[swz((wid << 4) + (lg << 2) + r, (ct << 4) + ln)] =
                    (unsigned int)php | ((unsigned int)plp << 16);
            }
        }

        // PV, 3-term split. s_p RAW is wave-local (rows wid*16..+15): no barrier.
        #pragma unroll
        for (int s2 = 0; s2 < 2; ++s2) {
            int pa = swz((wid << 4) + ln, (s2 << 5) + (lg << 3));
            uint4 w0 = *(const uint4*)&s_p[pa];
            uint4 w1 = *(const uint4*)&s_p[pa + 4];
            unsigned int wv[8] = {w0.x, w0.y, w0.z, w0.w, w1.x, w1.y, w1.z, w1.w};
            bf16x8 pfh, pfl;
            #pragma unroll
            for (int e = 0; e < 8; ++e) {
                pfh[e] = (short)(wv[e] & 0xffffu);
                pfl[e] = (short)(wv[e] >> 16);
            }
            #pragma unroll
            for (int dt = 0; dt < 4; ++dt) {
                int a = swz((dt << 4) + ln, (s2 << 5) + (lg << 3));
                bf16x8 vh = *(const bf16x8*)&s_vh[a];
                bf16x8 vl = *(const bf16x8*)&s_vl[a];
                oacc[dt] = __builtin_amdgcn_mfma_f32_16x16x32_bf16(pfh, vh, oacc[dt], 0, 0, 0);
                oacc[dt] = __builtin_amdgcn_mfma_f32_16x16x32_bf16(pfh, vl, oacc[dt], 0, 0, 0);
                oacc[dt] = __builtin_amdgcn_mfma_f32_16x16x32_bf16(pfl, vh, oacc[dt], 0, 0, 0);
            }
        }
        __syncthreads();
    }

    // epilogue: C/D layout row = lg*4+r, col = dt*16+ln
    float* op = Out + (rowBH + q0b + (wid << 4) + (lg << 2)) * DD + ln;
    #pragma unroll
    for (int dt = 0; dt < 4; ++dt)
        #pragma unroll
        for (int r = 0; r < 4; ++r)
            op[r * DD + (dt << 4)] = oacc[dt][r];
}

extern "C" void kernel_launch(void* const* d_in, const int* in_sizes, int n_in,
                              void* d_out, int out_size, void* d_ws, size_t ws_size,
                              hipStream_t stream) {
    const float* Q = (const float*)d_in[0];
    const float* K = (const float*)d_in[1];
    const float* V = (const float*)d_in[2];
    const float* M = (const float*)d_in[3];
    float* Out  = (float*)d_out;
    float* Attn = Out + (size_t)4 * HH * LL * DD;   // out first, then attn

    dim3 grid(LL / TQ, 4 * HH);
    dim3 block(NTH);
    attn_mfma<<<grid, block, 0, stream>>>(Q, K, V, M, Out, Attn);
}

// Round 3
// 1412.843 us; speedup vs baseline: 1.7019x; 1.0657x over previous
//
#include <hip/hip_runtime.h>

// Attention fwd, B=4 H=16 L=2048 D=64, fp32 in/out, outputs Out then Attn.
//
// Round 3 (resubmit; round-2 bench was an infra failure): split-bf16 MFMA
// with 2x larger wave output tile.
//  - TQ=128: wave owns 32 q-rows x 64 k-cols -> B-operand LDS reads, staging
//    work, and barriers per output HALVE; MFMA count unchanged.
//  - Q fragments loaded directly from global (no LDS staging / no Q barrier).
//  - T14-lite register prefetch: next tile's K/V global loads issue after the
//    mid barrier and complete under QK/exp/PV compute.
//  - s_p: u32 [128][66] (pad +2, no XOR) -> PV uint4 reads at the uniform
//    bank floor; total LDS 65.8 KB -> 2 blocks/CU.
//  - bf16 K/V tiles keep the GEMM-verified XOR swizzle col^=(row&7)<<3.
//  - XCD-grouped block swizzle: 8 consecutive bh per XCD (K/V L2-resident).
//  - s_setprio(1) around MFMA clusters (T5).
//  - Numerics identical to the round-1 passing kernel (absmax 0.0078).

#define LL 2048
#define DD 64
#define HH 16
#define TQ 128
#define TK 64
#define NTH 256
#define NKT (LL / TK)
#define SPD 66   // s_p row stride in u32 (odd*2 -> bank rotate, 33.8 KB)

typedef __attribute__((ext_vector_type(8))) short bf16x8;
typedef __attribute__((ext_vector_type(4))) float f32x4;

static __device__ __forceinline__ unsigned short bf_hi(float x) {
    return (unsigned short)(__float_as_uint(x) >> 16);   // truncating fp32->bf16
}
static __device__ __forceinline__ float bf_f(unsigned short h) {
    return __uint_as_float(((unsigned int)h) << 16);
}
// [rows][64] ushort arrays: XOR-swizzle 8-elem chunks within 8-row stripes
static __device__ __forceinline__ int swz(int row, int col) {
    return (row << 6) + (col ^ ((row & 7) << 3));
}

__global__ __launch_bounds__(NTH, 2)
void attn_mfma(const float* __restrict__ Q, const float* __restrict__ K,
               const float* __restrict__ V, const float* __restrict__ M,
               float* __restrict__ Out, float* __restrict__ Attn)
{
    __shared__ __align__(16) unsigned short s_kh[TK * DD];   // K hi  [k][d] 8KB
    __shared__ __align__(16) unsigned short s_kl[TK * DD];   // K lo
    __shared__ __align__(16) unsigned short s_vh[DD * TK];   // V^T hi [d][k]
    __shared__ __align__(16) unsigned short s_vl[DD * TK];   // V^T lo
    __shared__ __align__(16) unsigned int   s_p [TQ * SPD];  // P hi|lo<<16

    const int tid  = threadIdx.x;
    const int wid  = tid >> 6;        // wave 0..3: q-rows wid*32..+31
    const int lane = tid & 63;
    const int lg   = lane >> 4;       // 0..3
    const int ln   = lane & 15;       // 0..15

    // XCD-grouped swizzle: consecutive dispatch ids round-robin XCDs; remap so
    // each XCD gets a contiguous chunk of 128 work-ids = 8 bh (K/V fit its L2).
    int fid = blockIdx.y * 16 + blockIdx.x;
    fid = (fid & 7) * 128 + (fid >> 3);          // bijective, 1024 % 8 == 0
    const int bx = fid & 15;
    const int bh = fid >> 4;
    const int b  = bh >> 4;                      // HH = 16
    const int q0b = bx * TQ;
    const size_t rowBH = (size_t)bh * LL;

    // staging map for [64][64] tiles: 4 threads/row, 16 consecutive floats each
    const int sr  = tid >> 2;
    const int sc  = (tid & 3) << 4;
    // V^T staging: thread -> d = tid&63, k chunks vk0 + i*16
    const int vd  = tid & 63;
    const int vk0 = (tid >> 6) << 2;

    const float* Mrow = M + b * LL;
    const f32x4 fz = {0.f, 0.f, 0.f, 0.f};

    // ---- Q fragments direct from global (row = ln within 16-row tile rt) ----
    bf16x8 qh[2][2], ql[2][2];
    #pragma unroll
    for (int rt = 0; rt < 2; ++rt) {
        const float* qp = Q + (rowBH + q0b + (wid << 5) + (rt << 4) + ln) * DD;
        #pragma unroll
        for (int s = 0; s < 2; ++s) {
            float4 x0 = *(const float4*)(qp + (s << 5) + (lg << 3));
            float4 x1 = *(const float4*)(qp + (s << 5) + (lg << 3) + 4);
            float f[8] = {x0.x, x0.y, x0.z, x0.w, x1.x, x1.y, x1.z, x1.w};
            bf16x8 h, l;
            #pragma unroll
            for (int e = 0; e < 8; ++e) {
                unsigned short hh = bf_hi(f[e]);
                h[e] = (short)hh;
                l[e] = (short)bf_hi(f[e] - bf_f(hh));
            }
            qh[rt][s] = h;
            ql[rt][s] = l;
        }
    }

    // ================= sweep 1: row sums of exp (hi-only QK) =================
    float esum[2][4] = {};
    float4 kr[4];
    {
        const float* kp = K + (rowBH + sr) * DD + sc;
        #pragma unroll
        for (int i = 0; i < 4; ++i) kr[i] = *(const float4*)(kp + (i << 2));
    }
    for (int kt = 0; kt < NKT; ++kt) {
        #pragma unroll
        for (int i = 0; i < 4; ++i) {
            ushort4 h;
            h.x = bf_hi(kr[i].x); h.y = bf_hi(kr[i].y);
            h.z = bf_hi(kr[i].z); h.w = bf_hi(kr[i].w);
            *(ushort4*)&s_kh[swz(sr, sc + (i << 2))] = h;
        }
        __syncthreads();
        if (kt + 1 < NKT) {   // prefetch next K tile into registers
            const float* kp = K + (rowBH + (kt + 1) * TK + sr) * DD + sc;
            #pragma unroll
            for (int i = 0; i < 4; ++i) kr[i] = *(const float4*)(kp + (i << 2));
        }

        f32x4 acc[2][4];
        #pragma unroll
        for (int rt = 0; rt < 2; ++rt)
            #pragma unroll
            for (int ct = 0; ct < 4; ++ct) acc[rt][ct] = fz;

        __builtin_amdgcn_s_setprio(1);
        #pragma unroll
        for (int s = 0; s < 2; ++s) {
            #pragma unroll
            for (int ct = 0; ct < 4; ++ct) {
                bf16x8 kh = *(const bf16x8*)&s_kh[swz((ct << 4) + ln, (s << 5) + (lg << 3))];
                #pragma unroll
                for (int rt = 0; rt < 2; ++rt)
                    acc[rt][ct] = __builtin_amdgcn_mfma_f32_16x16x32_bf16(qh[rt][s], kh, acc[rt][ct], 0, 0, 0);
            }
        }
        __builtin_amdgcn_s_setprio(0);

        #pragma unroll
        for (int ct = 0; ct < 4; ++ct) {
            float mneg = Mrow[kt * TK + (ct << 4) + ln] * -1.0e9f;
            #pragma unroll
            for (int rt = 0; rt < 2; ++rt)
                #pragma unroll
                for (int r = 0; r < 4; ++r)
                    esum[rt][r] += __expf(fmaf(acc[rt][ct][r], 0.125f, mneg));
        }
        __syncthreads();
    }

    // in-wave reduction over the 16 ln lanes -> full row sums
    #pragma unroll
    for (int m = 1; m <= 8; m <<= 1)
        #pragma unroll
        for (int rt = 0; rt < 2; ++rt)
            #pragma unroll
            for (int r = 0; r < 4; ++r)
                esum[rt][r] += __shfl_xor(esum[rt][r], m, 64);
    float inv[2][4];
    #pragma unroll
    for (int rt = 0; rt < 2; ++rt)
        #pragma unroll
        for (int r = 0; r < 4; ++r) inv[rt][r] = 1.0f / esum[rt][r];

    // ================= sweep 2: attn store + PV (full split) =================
    f32x4 oacc[2][4];
    #pragma unroll
    for (int rt = 0; rt < 2; ++rt)
        #pragma unroll
        for (int dt = 0; dt < 4; ++dt) oacc[rt][dt] = fz;

    float4 kr2[4];
    float  vr[16];
    {
        const float* kp = K + (rowBH + sr) * DD + sc;
        #pragma unroll
        for (int i = 0; i < 4; ++i) kr2[i] = *(const float4*)(kp + (i << 2));
        const float* vbase = V + rowBH * DD + vd;
        #pragma unroll
        for (int i = 0; i < 4; ++i)
            #pragma unroll
            for (int j = 0; j < 4; ++j)
                vr[(i << 2) + j] = vbase[(vk0 + (i << 4) + j) * DD];
    }

    for (int kt = 0; kt < NKT; ++kt) {
        // stage K hi/lo and V^T hi/lo from prefetch registers
        #pragma unroll
        for (int i = 0; i < 4; ++i) {
            ushort4 h, l;
            h.x = bf_hi(kr2[i].x); l.x = bf_hi(kr2[i].x - bf_f(h.x));
            h.y = bf_hi(kr2[i].y); l.y = bf_hi(kr2[i].y - bf_f(h.y));
            h.z = bf_hi(kr2[i].z); l.z = bf_hi(kr2[i].z - bf_f(h.z));
            h.w = bf_hi(kr2[i].w); l.w = bf_hi(kr2[i].w - bf_f(h.w));
            int a = swz(sr, sc + (i << 2));
            *(ushort4*)&s_kh[a] = h;
            *(ushort4*)&s_kl[a] = l;
        }
        #pragma unroll
        for (int i = 0; i < 4; ++i) {
            ushort4 h, l;
            h.x = bf_hi(vr[(i << 2) + 0]); l.x = bf_hi(vr[(i << 2) + 0] - bf_f(h.x));
            h.y = bf_hi(vr[(i << 2) + 1]); l.y = bf_hi(vr[(i << 2) + 1] - bf_f(h.y));
            h.z = bf_hi(vr[(i << 2) + 2]); l.z = bf_hi(vr[(i << 2) + 2] - bf_f(h.z));
            h.w = bf_hi(vr[(i << 2) + 3]); l.w = bf_hi(vr[(i << 2) + 3] - bf_f(h.w));
            int a = swz(vd, vk0 + (i << 4));
            *(ushort4*)&s_vh[a] = h;
            *(ushort4*)&s_vl[a] = l;
        }
        __syncthreads();

        if (kt + 1 < NKT) {   // prefetch next K/V tiles (complete under compute)
            const float* kp = K + (rowBH + (kt + 1) * TK + sr) * DD + sc;
            #pragma unroll
            for (int i = 0; i < 4; ++i) kr2[i] = *(const float4*)(kp + (i << 2));
            const float* vbase = V + (rowBH + (kt + 1) * TK) * DD + vd;
            #pragma unroll
            for (int i = 0; i < 4; ++i)
                #pragma unroll
                for (int j = 0; j < 4; ++j)
                    vr[(i << 2) + j] = vbase[(vk0 + (i << 4) + j) * DD];
        }

        // QK^T, 3-term split
        f32x4 acc[2][4];
        #pragma unroll
        for (int rt = 0; rt < 2; ++rt)
            #pragma unroll
            for (int ct = 0; ct < 4; ++ct) acc[rt][ct] = fz;

        __builtin_amdgcn_s_setprio(1);
        #pragma unroll
        for (int s = 0; s < 2; ++s) {
            #pragma unroll
            for (int ct = 0; ct < 4; ++ct) {
                int a = swz((ct << 4) + ln, (s << 5) + (lg << 3));
                bf16x8 kh = *(const bf16x8*)&s_kh[a];
                bf16x8 kl = *(const bf16x8*)&s_kl[a];
                #pragma unroll
                for (int rt = 0; rt < 2; ++rt) {
                    acc[rt][ct] = __builtin_amdgcn_mfma_f32_16x16x32_bf16(qh[rt][s], kh, acc[rt][ct], 0, 0, 0);
                    acc[rt][ct] = __builtin_amdgcn_mfma_f32_16x16x32_bf16(qh[rt][s], kl, acc[rt][ct], 0, 0, 0);
                    acc[rt][ct] = __builtin_amdgcn_mfma_f32_16x16x32_bf16(ql[rt][s], kh, acc[rt][ct], 0, 0, 0);
                }
            }
        }
        __builtin_amdgcn_s_setprio(0);

        // normalize, store attn, pack P (hi|lo) into wave-private s_p rows
        #pragma unroll
        for (int rt = 0; rt < 2; ++rt) {
            const int prow = (wid << 5) + (rt << 4) + (lg << 2);
            float* ap = Attn + (rowBH + q0b + prow) * (size_t)LL + (size_t)kt * TK + ln;
            #pragma unroll
            for (int ct = 0; ct < 4; ++ct) {
                float mneg = Mrow[kt * TK + (ct << 4) + ln] * -1.0e9f;
                #pragma unroll
                for (int r = 0; r < 4; ++r) {
                    float p = __expf(fmaf(acc[rt][ct][r], 0.125f, mneg)) * inv[rt][r];
                    ap[(size_t)r * LL + (ct << 4)] = p;
                    unsigned short hp = bf_hi(p);
                    unsigned short lp = bf_hi(p - bf_f(hp));
                    s_p[(prow + r) * SPD + (ct << 4) + ln] =
                        (unsigned int)hp | ((unsigned int)lp << 16);
                }
            }
        }

        // PV, 3-term split (s_p RAW is wave-local: no barrier)
        #pragma unroll
        for (int s2 = 0; s2 < 2; ++s2) {
            bf16x8 pfh[2], pfl[2];
            #pragma unroll
            for (int rt = 0; rt < 2; ++rt) {
                const unsigned int* pp =
                    &s_p[((wid << 5) + (rt << 4) + ln) * SPD + (s2 << 5) + (lg << 3)];
                uint4 w0 = *(const uint4*)pp;
                uint4 w1 = *(const uint4*)(pp + 4);
                unsigned int wv[8] = {w0.x, w0.y, w0.z, w0.w, w1.x, w1.y, w1.z, w1.w};
                bf16x8 fh, fl;
                #pragma unroll
                for (int e = 0; e < 8; ++e) {
                    fh[e] = (short)(wv[e] & 0xffffu);
                    fl[e] = (short)(wv[e] >> 16);
                }
                pfh[rt] = fh;
                pfl[rt] = fl;
            }
            __builtin_amdgcn_s_setprio(1);
            #pragma unroll
            for (int dt = 0; dt < 4; ++dt) {
                int a = swz((dt << 4) + ln, (s2 << 5) + (lg << 3));
                bf16x8 vh = *(const bf16x8*)&s_vh[a];
                bf16x8 vl = *(const bf16x8*)&s_vl[a];
                #pragma unroll
                for (int rt = 0; rt < 2; ++rt) {
                    oacc[rt][dt] = __builtin_amdgcn_mfma_f32_16x16x32_bf16(pfh[rt], vh, oacc[rt][dt], 0, 0, 0);
                    oacc[rt][dt] = __builtin_amdgcn_mfma_f32_16x16x32_bf16(pfh[rt], vl, oacc[rt][dt], 0, 0, 0);
                    oacc[rt][dt] = __builtin_amdgcn_mfma_f32_16x16x32_bf16(pfl[rt], vh, oacc[rt][dt], 0, 0, 0);
                }
            }
            __builtin_amdgcn_s_setprio(0);
        }
        __syncthreads();
    }

    // epilogue: C/D layout row = lg*4+r, col = dt*16+ln
    #pragma unroll
    for (int rt = 0; rt < 2; ++rt) {
        float* op = Out + (rowBH + q0b + (wid << 5) + (rt << 4) + (lg << 2)) * DD + ln;
        #pragma unroll
        for (int dt = 0; dt < 4; ++dt)
            #pragma unroll
            for (int r = 0; r < 4; ++r)
                op[r * DD + (dt << 4)] = oacc[rt][dt][r];
    }
}

extern "C" void kernel_launch(void* const* d_in, const int* in_sizes, int n_in,
                              void* d_out, int out_size, void* d_ws, size_t ws_size,
                              hipStream_t stream) {
    const float* Q = (const float*)d_in[0];
    const float* K = (const float*)d_in[1];
    const float* V = (const float*)d_in[2];
    const float* M = (const float*)d_in[3];
    float* Out  = (float*)d_out;
    float* Attn = Out + (size_t)4 * HH * LL * DD;   // out first, then attn

    dim3 grid(LL / TQ, 4 * HH);
    dim3 block(NTH);
    attn_mfma<<<grid, block, 0, stream>>>(Q, K, V, M, Out, Attn);
}